// Round 9
// baseline (64.484 us; speedup 1.0000x reference)
//
#include <hip/hip_runtime.h>

// Problem constants (fixed by setup_inputs)
constexpr int T_TASKS = 256;
constexpr int NQ      = 300;
constexpr int NS      = 25;
constexpr int D       = 640;
constexpr int NWAY    = 5;
constexpr float LAMBDA_REG = 50.0f;

constexpr int SP4 = 161;        // float4 stride of one S row in LDS (644 floats)
constexpr int NT  = 1024;       // threads per block (16 waves)
constexpr int AC  = NS + NWAY;  // augmented columns = 30
constexpr int HALF_ROWS = 150;  // query rows per block (2 blocks per task)

// Pair-block table: 15 upper-triangle 5x5 blocks of the 25x25 Gram matrix
__device__ __constant__ int PA[15] = {0,0,0,0,0,1,1,1,1,2,2,2,3,3,4};
__device__ __constant__ int PB[15] = {0,1,2,3,4,1,2,3,4,2,3,4,3,4,4};

// ---------------------------------------------------------------------------
// Fused kernel, TWO blocks per task (each owns 150 query rows), 1024T.
//
// Accumulated design rules (R2-R8):
//  * 1024T blocks are pinned to 64 VGPR; the only spill-safe streaming loop
//    is round-per-row with 10 float4 in flight (~55 live regs) - R2's loop.
//  * Load hoisting under full unroll is the spill bomb: never fuse rows in
//    the stream loop (R6: 3 rows full-unroll -> 374MB scratch writes).
//  * No cross-barrier prefetch (R3-R5).
//  * R2 (1 block/CU, 16 waves) streamed at only ~4.8 TB/s: reduce/store
//    stall points not covered. This round: LDS 80,900B x2 = 161,800 fits
//    160KB -> 2 blocks/CU -> 32 streaming waves/CU, same per-wave pattern.
//  * Solve (~4us) duplicated in both half-blocks, runs concurrently.
// ---------------------------------------------------------------------------
__global__ __launch_bounds__(NT) void fused_ridge_head_kernel(
    const float* __restrict__ query,    // (T, NQ, D)
    const float* __restrict__ support,  // (T, NS, D)
    const float* __restrict__ scale,    // (1,)
    const int*   __restrict__ labels,   // (T, NS)
    float*       __restrict__ out)      // (T, NQ, NWAY)
{
    __shared__ __align__(16) float4 sS4[NS * SP4];   // 64,400 B
    __shared__ __align__(16) float  sW[NWAY][D];     // 12,800 B
    __shared__ float aug[NS][32];                    //  3,200 B
    __shared__ float sX[NS][NWAY];                   //    500 B  => 80,900 B

    const int blk  = blockIdx.x;
    const int t    = blk >> 1;
    const int half = blk & 1;
    const int tid  = threadIdx.x;
    const float* Sg    = support + (size_t)t * NS * D;
    const float* Qbase = query   + (size_t)t * NQ * D;
    const float sc = scale[0];

    // ---- A1: stage S into LDS (coalesced float4) + RHS init ----------------
    for (int idx = tid; idx < NS * 160; idx += NT) {
        int s = idx / 160, f = idx % 160;
        sS4[s * SP4 + f] = reinterpret_cast<const float4*>(Sg)[idx];
    }
    if (tid >= 960) {                       // wave 15: RHS = 2 * onehot
        for (int idx = tid - 960; idx < NS * NWAY; idx += 64) {
            int s = idx / NWAY, w = idx % NWAY;
            aug[s][NS + w] = (labels[t * NS + s] == w) ? 2.0f : 0.0f;
        }
    }
    __syncthreads();

    // ---- A2: K = S S^T + lambda I, 5x5 register-blocked (waves 0..3) -------
    // B row reloaded per-j: peak ~55 regs.
    if (tid < 240) {
        const int grp = tid >> 4, l = tid & 15;
        const int ra = PA[grp] * 5, rb = PB[grp] * 5;
        float acc[25] = {};
        #pragma unroll 2
        for (int k = 0; k < 10; ++k) {
            const int f = l + 16 * k;
            float4 A[5];
            #pragma unroll
            for (int r = 0; r < 5; ++r) A[r] = sS4[(ra + r) * SP4 + f];
            #pragma unroll
            for (int j = 0; j < 5; ++j) {
                float4 b = sS4[(rb + j) * SP4 + f];
                #pragma unroll
                for (int i = 0; i < 5; ++i)
                    acc[i * 5 + j] += A[i].x * b.x + A[i].y * b.y +
                                      A[i].z * b.z + A[i].w * b.w;
            }
        }
        #pragma unroll
        for (int p = 0; p < 25; ++p) {
            #pragma unroll
            for (int off = 8; off >= 1; off >>= 1)
                acc[p] += __shfl_xor(acc[p], off);
        }
        if (l == 0) {
            #pragma unroll
            for (int p = 0; p < 25; ++p) {
                int i = ra + p / 5, j = rb + p % 5;
                float v = acc[p] + (i == j ? LAMBDA_REG : 0.0f);
                aug[i][j] = v;
                aug[j][i] = v;
            }
        }
    }
    __syncthreads();

    // ---- A3 (wave 0): Gauss-Jordan in registers -> X into LDS --------------
    if (tid < 64) {
        const int  c      = tid;
        const bool active = (c < AC);
        float a[NS];
        #pragma unroll
        for (int r = 0; r < NS; ++r) a[r] = active ? aug[r][c] : 0.0f;
        #pragma unroll
        for (int k = 0; k < NS; ++k) {
            float piv = __shfl(a[k], k);    // aug[k][k]
            float inv = 1.0f / piv;
            a[k] *= inv;
            #pragma unroll
            for (int r = 0; r < NS; ++r) {
                if (r != k) {
                    float m = __shfl(a[r], k);
                    a[r] -= m * a[k];
                }
            }
        }
        if (active && c >= NS) {            // RHS columns now hold X = 2 K^-1 Y
            const int w = c - NS;
            #pragma unroll
            for (int s = 0; s < NS; ++s) sX[s][w] = a[s];
        }
    }
    __syncthreads();

    // ---- A4: W[w][d] = sum_s S[s][d] * X[s][w]  (tid < 640) ----------------
    if (tid < D) {
        const float* sSf = reinterpret_cast<const float*>(sS4);
        float acc[NWAY] = {};
        #pragma unroll
        for (int s = 0; s < NS; ++s) {
            float sv = sSf[s * (SP4 * 4) + tid];
            #pragma unroll
            for (int w = 0; w < NWAY; ++w) acc[w] += sv * sX[s][w];
        }
        #pragma unroll
        for (int w = 0; w < NWAY; ++w) sW[w][tid] = acc[w];
    }
    __syncthreads();

    // ---- Phase B: logits = scale * Q W, round-per-row (R2's exact loop) ----
    // Block owns rows [half*150, half*150+150): rounds r = g, g+64, g+128.
    const int g  = tid >> 4;
    const int l4 = tid & 15;
    const float4* Qb4 = reinterpret_cast<const float4*>(Qbase);

    #pragma unroll
    for (int j = 0; j < 3; ++j) {
        const int  r  = j * 64 + g;               // 0..191
        const bool ok = (r < HALF_ROWS);          // exec-masked tail (r<150)
        const int  q  = half * HALF_ROWS + r;
        const int  off = q * 160 + l4;
        float acc[NWAY] = {};
        if (ok) {
            #pragma unroll
            for (int i = 0; i < 10; ++i) {        // 10 float4 in flight
                float4 qv = Qb4[off + i * 16];
                const int dbase = i * 64 + 4 * l4;
                #pragma unroll
                for (int w = 0; w < NWAY; ++w) {
                    const float4 wv = *reinterpret_cast<const float4*>(&sW[w][dbase]);
                    acc[w] += qv.x * wv.x + qv.y * wv.y + qv.z * wv.z + qv.w * wv.w;
                }
            }
        }
        #pragma unroll
        for (int w = 0; w < NWAY; ++w) {
            #pragma unroll
            for (int o = 8; o >= 1; o >>= 1)
                acc[w] += __shfl_xor(acc[w], o);
        }
        float ov = acc[0];
        ov = (l4 == 1) ? acc[1] : ov;
        ov = (l4 == 2) ? acc[2] : ov;
        ov = (l4 == 3) ? acc[3] : ov;
        ov = (l4 == 4) ? acc[4] : ov;
        if (ok && l4 < NWAY)
            out[((size_t)t * NQ + q) * NWAY + l4] = sc * ov;
    }
}

extern "C" void kernel_launch(void* const* d_in, const int* in_sizes, int n_in,
                              void* d_out, int out_size, void* d_ws, size_t ws_size,
                              hipStream_t stream) {
    const float* query   = (const float*)d_in[0];
    const float* support = (const float*)d_in[1];
    const float* scale   = (const float*)d_in[2];
    const int*   labels  = (const int*)d_in[3];
    float* out = (float*)d_out;

    fused_ridge_head_kernel<<<T_TASKS * 2, NT, 0, stream>>>(query, support, scale, labels, out);
}

// Round 10
// 61.785 us; speedup vs baseline: 1.0437x; 1.0437x over previous
//
#include <hip/hip_runtime.h>

// Problem constants (fixed by setup_inputs)
constexpr int T_TASKS = 256;
constexpr int NQ      = 300;
constexpr int NS      = 25;
constexpr int D       = 640;
constexpr int NWAY    = 5;
constexpr float LAMBDA_REG = 50.0f;

constexpr int SP4 = 161;        // float4 stride of one S row in LDS (644 floats)
constexpr int AC  = NS + NWAY;  // augmented columns = 30
constexpr int ROWS_PER_BLK = 64;
constexpr int CHUNKS = 5;       // 5 * 64 = 320 >= 300 rows, tail masked

// Pair-block table: 15 upper-triangle 5x5 blocks of the 25x25 Gram matrix
__device__ __constant__ int PA[15] = {0,0,0,0,0,1,1,1,1,2,2,2,3,3,4};
__device__ __constant__ int PB[15] = {0,1,2,3,4,1,2,3,4,2,3,4,3,4,4};

// ---------------------------------------------------------------------------
// UNIFYING DIAGNOSIS (R2..R9): every Phase-B variant used 16-lane groups per
// query row -> 50 wave-wide ds_read_b128 per row with only 256B distinct data
// each (4 groups read identical addresses). 300 rows x 50 x ~8cyc = ~50us of
// LDS issue per CU = the observed 48-64us plateau, regardless of occupancy.
// FIX (K2): wave = TWO rows (lanes 0-31 / 32-63), lane covers d-slots
// {hl+32k}: 25 b128 per 2 rows, each 1024B-distinct (2-way broadcast free).
// LDS floor drops 50us -> ~6us; kernel becomes HBM-bound on the Q stream.
// ---------------------------------------------------------------------------

// K1: per-task ridge solve -> wmat[t][w][d] in workspace. (proven in R8)
__global__ __launch_bounds__(256) void ridge_solve_kernel(
    const float* __restrict__ support,   // (T, NS, D)
    const int*   __restrict__ labels,    // (T, NS)
    float*       __restrict__ wmat)      // (T, NWAY, D)
{
    __shared__ __align__(16) float4 sS4[NS * SP4];   // 64,400 B
    __shared__ float aug[NS][32];
    __shared__ float sX[NS][NWAY];

    const int t   = blockIdx.x;
    const int tid = threadIdx.x;
    const float* Sg = support + (size_t)t * NS * D;

    for (int idx = tid; idx < NS * 160; idx += 256) {
        int s = idx / 160, f = idx % 160;
        sS4[s * SP4 + f] = reinterpret_cast<const float4*>(Sg)[idx];
    }
    if (tid < NS * NWAY) {              // RHS = 2 * onehot
        int s = tid / NWAY, w = tid % NWAY;
        aug[s][NS + w] = (labels[t * NS + s] == w) ? 2.0f : 0.0f;
    }
    __syncthreads();

    // Gram: K = S S^T + lambda I, 15 pair-blocks x 16 lanes (threads 0..239).
    if (tid < 240) {
        const int grp = tid >> 4, l = tid & 15;
        const int ra = PA[grp] * 5, rb = PB[grp] * 5;
        float acc[25] = {};
        #pragma unroll 2
        for (int k = 0; k < 10; ++k) {
            const int f = l + 16 * k;
            float4 A[5];
            #pragma unroll
            for (int r = 0; r < 5; ++r) A[r] = sS4[(ra + r) * SP4 + f];
            #pragma unroll
            for (int j = 0; j < 5; ++j) {
                float4 b = sS4[(rb + j) * SP4 + f];
                #pragma unroll
                for (int i = 0; i < 5; ++i)
                    acc[i * 5 + j] += A[i].x * b.x + A[i].y * b.y +
                                      A[i].z * b.z + A[i].w * b.w;
            }
        }
        #pragma unroll
        for (int p = 0; p < 25; ++p) {
            #pragma unroll
            for (int off = 8; off >= 1; off >>= 1)
                acc[p] += __shfl_xor(acc[p], off);
        }
        if (l == 0) {
            #pragma unroll
            for (int p = 0; p < 25; ++p) {
                int i = ra + p / 5, j = rb + p % 5;
                float v = acc[p] + (i == j ? LAMBDA_REG : 0.0f);
                aug[i][j] = v;
                aug[j][i] = v;
            }
        }
    }
    __syncthreads();

    // Gauss-Jordan in wave-0 registers; lane c owns column c of 25x30 system.
    if (tid < 64) {
        const int  c      = tid;
        const bool active = (c < AC);
        float a[NS];
        #pragma unroll
        for (int r = 0; r < NS; ++r) a[r] = active ? aug[r][c] : 0.0f;
        #pragma unroll
        for (int k = 0; k < NS; ++k) {
            float piv = __shfl(a[k], k);
            float inv = 1.0f / piv;
            a[k] *= inv;
            #pragma unroll
            for (int r = 0; r < NS; ++r) {
                if (r != k) {
                    float m = __shfl(a[r], k);
                    a[r] -= m * a[k];
                }
            }
        }
        if (active && c >= NS) {        // RHS columns hold X = 2 K^-1 Y
            const int w = c - NS;
            #pragma unroll
            for (int s = 0; s < NS; ++s) sX[s][w] = a[s];
        }
    }
    __syncthreads();

    // W[w][d] = sum_s S[s][d] * X[s][w]
    const float* sSf = reinterpret_cast<const float*>(sS4);
    #pragma unroll
    for (int ii = 0; ii < 3; ++ii) {
        const int d = tid + 256 * ii;
        if (d < D) {
            float acc[NWAY] = {};
            #pragma unroll
            for (int s = 0; s < NS; ++s) {
                float sv = sSf[s * (SP4 * 4) + d];
                #pragma unroll
                for (int w = 0; w < NWAY; ++w) acc[w] += sv * sX[s][w];
            }
            #pragma unroll
            for (int w = 0; w < NWAY; ++w)
                wmat[((size_t)t * NWAY + w) * D + d] = acc[w];
        }
    }
}

// K2: logits = scale * Q W. Grid 1280 (5 blocks/task), 256T (4 waves).
// Wave = 2 rows per round: lanes 0-31 row q, lanes 32-63 row q+1.
// Lane hl covers d-slots {hl+32k, k=0..4}; W reads are 2-way-broadcast
// (free) and 1024B-distinct; Q loads coalesced 512B per half-wave.
__global__ __launch_bounds__(256) void logits_kernel(
    const float* __restrict__ query,   // (T, NQ, D)
    const float* __restrict__ wmat,    // (T, NWAY, D)
    const float* __restrict__ scale,   // (1,)
    float*       __restrict__ out)     // (T, NQ, NWAY)
{
    __shared__ __align__(16) float4 sW4[NWAY * 160];   // 12,800 B

    const int b     = blockIdx.x;
    const int t     = b / CHUNKS;
    const int chunk = b % CHUNKS;
    const int tid   = threadIdx.x;

    {
        const float4* Wg = reinterpret_cast<const float4*>(wmat + (size_t)t * NWAY * D);
        for (int idx = tid; idx < NWAY * 160; idx += 256)
            sW4[idx] = Wg[idx];
    }
    __syncthreads();

    const float sc   = scale[0];
    const int   wave = tid >> 6;
    const int   hl   = tid & 31;          // lane within half-wave
    const int   half = (tid >> 5) & 1;    // 0: row q, 1: row q+1
    const float4* Qb4 = reinterpret_cast<const float4*>(query + (size_t)t * NQ * D);
    float* outT = out + (size_t)t * NQ * NWAY;

    const int base = chunk * ROWS_PER_BLK + wave * 16 + half;

    for (int r = 0; r < 8; ++r) {
        const int  q  = base + 2 * r;
        const bool ok = (q < NQ);                 // tail masked (no traffic)
        float acc[NWAY] = {};
        if (ok) {
            const int qoff = q * 160 + hl;
            float4 qv0 = Qb4[qoff];
            float4 qv1 = Qb4[qoff + 32];
            float4 qv2 = Qb4[qoff + 64];
            float4 qv3 = Qb4[qoff + 96];
            float4 qv4 = Qb4[qoff + 128];
            #pragma unroll
            for (int w = 0; w < NWAY; ++w) {
                const int wb = w * 160 + hl;
                float4 wv0 = sW4[wb];
                float4 wv1 = sW4[wb + 32];
                float4 wv2 = sW4[wb + 64];
                float4 wv3 = sW4[wb + 96];
                float4 wv4 = sW4[wb + 128];
                acc[w] += qv0.x * wv0.x + qv0.y * wv0.y + qv0.z * wv0.z + qv0.w * wv0.w;
                acc[w] += qv1.x * wv1.x + qv1.y * wv1.y + qv1.z * wv1.z + qv1.w * wv1.w;
                acc[w] += qv2.x * wv2.x + qv2.y * wv2.y + qv2.z * wv2.z + qv2.w * wv2.w;
                acc[w] += qv3.x * wv3.x + qv3.y * wv3.y + qv3.z * wv3.z + qv3.w * wv3.w;
                acc[w] += qv4.x * wv4.x + qv4.y * wv4.y + qv4.z * wv4.z + qv4.w * wv4.w;
            }
        }
        // reduce within each 32-lane half (xor offsets never cross bit 5)
        #pragma unroll
        for (int w = 0; w < NWAY; ++w) {
            #pragma unroll
            for (int o = 16; o >= 1; o >>= 1)
                acc[w] += __shfl_xor(acc[w], o);
        }
        float ov = acc[0];
        ov = (hl == 1) ? acc[1] : ov;
        ov = (hl == 2) ? acc[2] : ov;
        ov = (hl == 3) ? acc[3] : ov;
        ov = (hl == 4) ? acc[4] : ov;
        if (ok && hl < NWAY)
            outT[q * NWAY + hl] = sc * ov;
    }
}

extern "C" void kernel_launch(void* const* d_in, const int* in_sizes, int n_in,
                              void* d_out, int out_size, void* d_ws, size_t ws_size,
                              hipStream_t stream) {
    const float* query   = (const float*)d_in[0];
    const float* support = (const float*)d_in[1];
    const float* scale   = (const float*)d_in[2];
    const int*   labels  = (const int*)d_in[3];

    float* wmat = (float*)d_ws;          // T*NWAY*D*4 = 3,276,800 B
    float* out  = (float*)d_out;

    ridge_solve_kernel<<<T_TASKS, 256, 0, stream>>>(support, labels, wmat);
    logits_kernel<<<T_TASKS * CHUNKS, 256, 0, stream>>>(query, wmat, scale, out);
}